// Round 1
// baseline (416.410 us; speedup 1.0000x reference)
//
#include <hip/hip_runtime.h>
#include <math.h>

// Problem constants (from reference)
#define K_SHEET   0.01f
#define K_CHAN    0.1f
#define CAV_SPACE 2.0f
#define FLOW_EXP  1.25f

// DISS = (1/917 - 1/1000)/3.34e5, computed in double, used as f32 (matches jnp cast)
__device__ __constant__ float c_diss = (float)((1.0 / 917.0 - 1.0 / 1000.0) / 3.34e5);

// One thread per node (= per matrix row). Matrix has been zeroed by memset.
// Row i gets: diag = sum of per-slot terms, off-diag at column adj[i,s] = -term.
// Dirichlet (boundary) rows: identity row -> just M[i,i] = 1.
__global__ void sgds_patch_kernel(const float* __restrict__ pot,        // [N]
                                  const float* __restrict__ chan,       // [L]
                                  const float* __restrict__ sheet,      // [N]
                                  const float* __restrict__ face_len,   // [L]
                                  const float* __restrict__ link_len,   // [L]
                                  const int*   __restrict__ adj,        // [N,4]
                                  const int*   __restrict__ lnk,        // [N,4]
                                  const int*   __restrict__ face_at_link, // [L]
                                  const int*   __restrict__ head,       // [L]
                                  const int*   __restrict__ tail,       // [L]
                                  const int*   __restrict__ inout,      // [N]
                                  float*       __restrict__ M,          // [N,N]
                                  int N)
{
    int i = blockIdx.x * blockDim.x + threadIdx.x;
    if (i >= N) return;

    float* row = M + (size_t)i * (size_t)N;

    if (inout[i] == 1) {
        // Dirichlet row: identity (rest of row already zero from memset)
        row[i] = 1.0f;
        return;
    }

    float diag = 0.0f;

    #pragma unroll
    for (int s = 0; s < 4; ++s) {
        int j = adj[i * 4 + s];
        if (j < 0) continue;                 // masked slot contributes nothing
        int lid = lnk[i * 4 + s];

        // link fields (recomputed on the fly; trivially cheap)
        int   h  = head[lid];
        int   t  = tail[lid];
        float ll = link_len[lid];
        float g  = (pot[h] - pot[t]) / ll;   // grad[lid]

        float cq  = -K_CHAN * powf(chan[lid], FLOW_EXP) * g;            // chan_q[lid]
        float stl = 0.5f * (sheet[h] + sheet[t]);
        float ginv_sqrt = 1.0f / sqrtf(fabsf(g));                        // |g|^-0.5 (inf at 0, like numpy)
        float sq  = -K_SHEET * powf(stl, FLOW_EXP) * ginv_sqrt * g;      // sheet_q[lid]

        // per (node, slot) fields
        float fl = face_len[face_at_link[lid]];
        // NOTE: reference indexes channel_size (link field) by NODE ids — reproduced faithfully.
        float cs = 0.5f * (chan[i] + chan[j]);
        float st = 0.5f * (sheet[i] + sheet[j]);

        float sheet_flux = -K_SHEET * powf(st, FLOW_EXP) * ginv_sqrt * fl / ll;
        float chan_flux  = -K_CHAN  * powf(cs, FLOW_EXP) * fl / ll;
        float ch_diss    = fabsf(c_diss * cq * fl);
        float sh_diss    = fabsf(c_diss * sq * CAV_SPACE * fl);

        float term = sheet_flux + chan_flux + ch_diss + sh_diss;

        row[j] = -term;      // off-diagonal scatter (row-private: no races)
        diag  += term;
    }

    row[i] = diag;
}

extern "C" void kernel_launch(void* const* d_in, const int* in_sizes, int n_in,
                              void* d_out, int out_size, void* d_ws, size_t ws_size,
                              hipStream_t stream) {
    const float* pot      = (const float*)d_in[0];   // previous_potential [N]
    const float* chan     = (const float*)d_in[1];   // channel_size [L]
    const float* sheet    = (const float*)d_in[2];   // sheet_thickness [N]
    const float* face_len = (const float*)d_in[3];   // length_of_face [L]
    const float* link_len = (const float*)d_in[4];   // length_of_link [L]
    const int*   adj      = (const int*)d_in[5];     // adjacent_nodes [N,4]
    const int*   lnk      = (const int*)d_in[6];     // links_at_node [N,4]
    const int*   fal      = (const int*)d_in[7];     // face_at_link [L]
    const int*   head     = (const int*)d_in[8];     // link_head [L]
    const int*   tail     = (const int*)d_in[9];     // link_tail [L]
    const int*   inout    = (const int*)d_in[10];    // inflow_outflow [N]

    float* M = (float*)d_out;
    int N = in_sizes[0];                             // 10000

    // Pass 1: zero the dense matrix (the unavoidable 400 MB write — this is the roofline)
    hipMemsetAsync(d_out, 0, (size_t)out_size * sizeof(float), stream);

    // Pass 2: patch the <=5 nonzeros per row (tiny)
    int block = 256;
    int grid  = (N + block - 1) / block;
    sgds_patch_kernel<<<grid, block, 0, stream>>>(pot, chan, sheet, face_len, link_len,
                                                  adj, lnk, fal, head, tail, inout, M, N);
}